// Round 14
// baseline (104.645 us; speedup 1.0000x reference)
//
#include <hip/hip_runtime.h>
#include <math.h>

#define CIN   128
#define COUT  256
#define HH    64
#define WW    64
#define BB    4
#define KK    9
#define CK    (CIN*KK)   // 1152

typedef unsigned short u16;
typedef unsigned int   u32;
using f32x4  = __attribute__((ext_vector_type(4))) float;
using s16x8  = __attribute__((ext_vector_type(8))) short;

__device__ __forceinline__ u16 f2bf(float f) {
    union { float f; u32 u; } v; v.f = f;
    u32 u = v.u;
    u += 0x7FFFu + ((u >> 16) & 1u);   // round-to-nearest-even
    return (u16)(u >> 16);
}
__device__ __forceinline__ float bfel(s16x8 v, int j) {
    union { u32 u; float f; } c; c.u = ((u32)(u16)v[j]) << 16; return c.f;
}
__device__ __forceinline__ u32 asu(float f) {
    union { float f; u32 u; } v; v.f = f; return v.u;
}

// -------------------------------------------------------------------------
// prep_all (identical to round 11/13): xt NHWC bf16; W fragment-ordered:
//  wfrag idx = ((((tap*8+wv)*2+t)*4+ks4)*512) + lane*8 + j   (8KB/tap/wave)
//  wofsf idx = (((tap*2+t)*4+ks4)*512) + lane*8 + j          (8KB/tap)
// -------------------------------------------------------------------------
__global__ __launch_bounds__(256)
void prep_all(const float* __restrict__ x, const float* __restrict__ w,
              const float* __restrict__ ow, const float* __restrict__ mw,
              u16* __restrict__ xt, u16* __restrict__ wfrag,
              u16* __restrict__ wofsf) {
    __shared__ u16 T[64][130];
    int blk = blockIdx.x;
    int tid = threadIdx.x;

    if (blk < 256) {                         // ---- xprep ----
        int b = blk >> 6, y = blk & 63;
        int lane = tid & 63, cw = tid >> 6;
        for (int c = cw; c < 128; c += 4)
            T[lane][c] = f2bf(x[((b * 128 + c) * 64 + y) * 64 + lane]);
        __syncthreads();
        int c = tid & 127;
        for (int p = tid >> 7; p < 64; p += 2)
            xt[((b * 64 + y) * 64 + p) * 128 + c] = T[p][c];
    } else if (blk < 256 + 1152) {           // ---- wprep ----
        int i = (blk - 256) * 256 + tid;
        int j    = i & 7;
        int lane = (i >> 3) & 63;
        int ks4  = (i >> 9) & 3;
        int t    = (i >> 11) & 1;
        int wv   = (i >> 12) & 7;
        int tap  = i >> 15;                  // 0..8
        int co = (wv * 2 + t) * 16 + (lane & 15);
        int k  = tap * 128 + ks4 * 32 + (lane >> 4) * 8 + j;
        int c  = k & 127;
        wfrag[i] = f2bf(w[co * CK + c * 9 + tap]);
    } else {                                 // ---- wofs_prep ----
        int i = (blk - 1408) * 256 + tid;
        if (i < 9 * 4096) {
            int j    = i & 7;
            int lane = (i >> 3) & 63;
            int ks4  = (i >> 9) & 3;
            int t    = (i >> 11) & 1;
            int tap  = i >> 12;              // 0..8
            int co = t * 16 + (lane & 15);
            int k  = tap * 128 + ks4 * 32 + (lane >> 4) * 8 + j;
            int c  = k & 127;
            float v = 0.f;
            if (co < 18)      v = ow[co * CK + c * 9 + tap];
            else if (co < 27) v = mw[(co - 18) * CK + c * 9 + tap];
            wofsf[i] = f2bf(v);
        }
    }
}

// -------------------------------------------------------------------------
// Fused kernel, round-14: phase A rewritten BARRIER-FREE — regular-grid
// B-fragments are direct 16B global loads from xt (lane l16 = px, quad ->
// channel oct), waves 0..3 each own (co-tile, px-half), waves 4..7 skip
// to the post-A barrier. Phase B identical to r13 (two taps per barrier,
// 4-slot Sm). Same element values + accumulation order -> bitwise-identical
// output vs r13.
// -------------------------------------------------------------------------
__global__ __launch_bounds__(512, 4)
void dcn_fused(const u16* __restrict__ xt, const u16* __restrict__ wofsf,
               const float* __restrict__ ob, const float* __restrict__ mb,
               const u16* __restrict__ wfrag, float* __restrict__ out) {
    int blkid = blockIdx.x;          // 512 = BB*HH*2
    int xcd = blkid & 7, idx = blkid >> 3;
    int b   = xcd >> 1;
    int ho  = ((xcd & 1) << 5) + (idx >> 1);
    int wo0 = (idx & 1) << 5;
    int tid = threadIdx.x;

    __shared__ __align__(16) u16 Sm[4][32][136];  // 34.8 KB, 4 tap slots
    __shared__ float s_om[27][32];
    __shared__ int   s_idx[32][KK][4];  // corner pos * 128 (xt units)
    __shared__ float s_wgt[32][KK][4];

    int wv   = tid >> 6, lane = tid & 63;
    int quad = lane >> 4, l16 = lane & 15;
    int gpx  = wv * 4 + (lane >> 4);    // px this lane stages (0..31)
    int oct  = lane & 15;               // channel-oct (8 ch)

    const u16* xtb = xt + (size_t)b * 4096 * 128;
    const s16x8 vzero = {0,0,0,0,0,0,0,0};

    // ========= phase A: offset/mask GEMM, barrier-free direct loads =========
    if (wv < 4) {
        int t  = wv >> 1;                // co-tile 0/1
        int ph = wv & 1;                 // px half
        int wo = wo0 + ph * 16 + l16;    // this lane's output column
        f32x4 aco = (f32x4)(0.f);

        s16x8 bA[2][4];
        auto loadB = [&](int tap, int slot) {
            int kx = tap % 3;
            int y  = ho - 1 + tap / 3;
            int col = wo + kx - 1;
            bool ok = ((unsigned)y < HH) && ((unsigned)col < WW);
            int yc = ok ? y : 0, cc = ok ? col : 0;
            const u16* base = xtb + (size_t)(yc * 64 + cc) * 128 + quad * 8;
#pragma unroll
            for (int ks4 = 0; ks4 < 4; ++ks4) {
                s16x8 v = *(const s16x8*)(base + ks4 * 32);
                bA[slot][ks4] = ok ? v : vzero;
            }
        };

        loadB(0, 0);
        loadB(1, 1);
#pragma unroll
        for (int tap = 0; tap < 9; ++tap) {
            int sl = tap & 1;
            const u16* wc = wofsf + (tap * 2 + t) * 2048 + lane * 8;
#pragma unroll
            for (int ks4 = 0; ks4 < 4; ++ks4) {
                s16x8 afrag = *(const s16x8*)(wc + ks4 * 512);
                aco = __builtin_amdgcn_mfma_f32_16x16x32_bf16(afrag, bA[sl][ks4], aco, 0, 0, 0);
            }
            if (tap + 2 < 9) loadB(tap + 2, sl);   // overlaps next MFMAs
        }

        // epilogue A: co = t*16 + quad*4 + r; px column ph*16+l16
#pragma unroll
        for (int r = 0; r < 4; ++r) {
            int co = t * 16 + quad * 4 + r;
            if (co < 27) {
                float v = aco[r];
                if (co < 18) {
                    v += ob[co];
                    v = fminf(fmaxf(v, -16.f), 16.f);   // max_offset = 16
                } else {
                    v += mb[co - 18];
                    v = 2.f / (1.f + expf(-v));         // 2*sigmoid
                }
                s_om[co][ph * 16 + l16] = v;
            }
        }
    }
    __syncthreads();   // waves 4..7 wait here; s_om now complete

    // bilinear corner params for 32 px x 9 taps
    if (tid < 32 * KK) {
        int p = tid / KK, k = tid - (tid / KK) * KK;
        int wo = wo0 + p;
        float offy = s_om[2 * k][p];
        float offx = s_om[2 * k + 1][p];
        float mval = s_om[18 + k][p];

        float py = (float)(ho - 1 + k / 3) + offy;
        float px = (float)(wo - 1 + k % 3) + offx;
        float y0f = floorf(py), x0f = floorf(px);
        float wy1 = py - y0f,  wx1 = px - x0f;
        float wy0 = 1.f - wy1, wx0 = 1.f - wx1;
        int iy0 = (int)y0f, ix0 = (int)x0f;
        int iy1 = iy0 + 1,  ix1 = ix0 + 1;
        bool vy0 = (iy0 >= 0) && (iy0 < HH);
        bool vy1 = (iy1 >= 0) && (iy1 < HH);
        bool vx0 = (ix0 >= 0) && (ix0 < WW);
        bool vx1 = (ix1 >= 0) && (ix1 < WW);
        int cy0 = min(max(iy0, 0), HH - 1), cy1 = min(max(iy1, 0), HH - 1);
        int cx0 = min(max(ix0, 0), WW - 1), cx1 = min(max(ix1, 0), WW - 1);
        s_idx[p][k][0] = (cy0 * WW + cx0) * 128;
        s_idx[p][k][1] = (cy0 * WW + cx1) * 128;
        s_idx[p][k][2] = (cy1 * WW + cx0) * 128;
        s_idx[p][k][3] = (cy1 * WW + cx1) * 128;
        s_wgt[p][k][0] = (vy0 && vx0) ? mval * wy0 * wx0 : 0.f;
        s_wgt[p][k][1] = (vy0 && vx1) ? mval * wy0 * wx1 : 0.f;
        s_wgt[p][k][2] = (vy1 && vx0) ? mval * wy1 * wx0 : 0.f;
        s_wgt[p][k][3] = (vy1 && vx1) ? mval * wy1 * wx1 : 0.f;
    }
    __syncthreads();

    // ================= phase B: sampling + main GEMM (r13) =================
    f32x4 acc[2][2];                 // [co-tile t][px half ph]
#pragma unroll
    for (int t = 0; t < 2; ++t) { acc[t][0] = (f32x4)(0.f); acc[t][1] = (f32x4)(0.f); }

    s16x8 crs[2][2][4];              // [slot-pair][tap-in-pair][corner]
    float gs[2][2][4];
    auto gatherB = [&](int tap, int sp, int ti) {
        int i0 = s_idx[gpx][tap][0], i1 = s_idx[gpx][tap][1];
        int i2 = s_idx[gpx][tap][2], i3 = s_idx[gpx][tap][3];
        gs[sp][ti][0] = s_wgt[gpx][tap][0]; gs[sp][ti][1] = s_wgt[gpx][tap][1];
        gs[sp][ti][2] = s_wgt[gpx][tap][2]; gs[sp][ti][3] = s_wgt[gpx][tap][3];
        int co8 = oct * 8;
        crs[sp][ti][0] = *(const s16x8*)(xtb + i0 + co8);
        crs[sp][ti][1] = *(const s16x8*)(xtb + i1 + co8);
        crs[sp][ti][2] = *(const s16x8*)(xtb + i2 + co8);
        crs[sp][ti][3] = *(const s16x8*)(xtb + i3 + co8);
    };

    auto blend_store = [&](int sp, int ti, int slot) {
        float g0 = gs[sp][ti][0], g1 = gs[sp][ti][1];
        float g2 = gs[sp][ti][2], g3 = gs[sp][ti][3];
        float o[8];
#pragma unroll
        for (int j = 0; j < 8; ++j)
            o[j] = g0 * bfel(crs[sp][ti][0], j) + g1 * bfel(crs[sp][ti][1], j)
                 + g2 * bfel(crs[sp][ti][2], j) + g3 * bfel(crs[sp][ti][3], j);
        uint4 pkv;
        pkv.x = (asu(o[1]) & 0xFFFF0000u) | (asu(o[0]) >> 16);
        pkv.y = (asu(o[3]) & 0xFFFF0000u) | (asu(o[2]) >> 16);
        pkv.z = (asu(o[5]) & 0xFFFF0000u) | (asu(o[4]) >> 16);
        pkv.w = (asu(o[7]) & 0xFFFF0000u) | (asu(o[6]) >> 16);
        *(uint4*)(&Sm[slot][gpx][oct * 8]) = pkv;
    };

    auto pb_mfma_tap = [&](int tap, int slot) {
        const u16* wc = wfrag + (tap * 8 + wv) * 4096 + lane * 8;
        s16x8 af[8];
#pragma unroll
        for (int t = 0; t < 2; ++t)
#pragma unroll
            for (int ks4 = 0; ks4 < 4; ++ks4)
                af[t * 4 + ks4] = *(const s16x8*)(wc + (t * 4 + ks4) * 512);
#pragma unroll
        for (int ks4 = 0; ks4 < 4; ++ks4) {
            s16x8 bf0 = *(const s16x8*)(&Sm[slot][l16][ks4 * 32 + quad * 8]);
            s16x8 bf1 = *(const s16x8*)(&Sm[slot][16 + l16][ks4 * 32 + quad * 8]);
#pragma unroll
            for (int t = 0; t < 2; ++t) {
                acc[t][0] = __builtin_amdgcn_mfma_f32_16x16x32_bf16(af[t * 4 + ks4], bf0, acc[t][0], 0, 0, 0);
                acc[t][1] = __builtin_amdgcn_mfma_f32_16x16x32_bf16(af[t * 4 + ks4], bf1, acc[t][1], 0, 0, 0);
            }
        }
    };

    gatherB(0, 0, 0);
    gatherB(1, 0, 1);
    int buf = 0;
#pragma unroll
    for (int p = 0; p < 4; ++p) {       // tap pairs (0,1)(2,3)(4,5)(6,7)
        int sp = p & 1;
        blend_store(sp, 0, 2 * sp);
        blend_store(sp, 1, 2 * sp + 1);
        __syncthreads();
        if (p < 3) { gatherB(2 * p + 2, sp ^ 1, 0); gatherB(2 * p + 3, sp ^ 1, 1); }
        else       { gatherB(8,         sp ^ 1, 0); }
        pb_mfma_tap(2 * p,     2 * sp);
        pb_mfma_tap(2 * p + 1, 2 * sp + 1);
    }
    // tail: tap 8
    blend_store(0, 0, 0);
    __syncthreads();
    pb_mfma_tap(8, 0);

    // epilogue: co = (wv*2+t)*16 + quad*4 + r; px = wo0 + ph*16 + l16
#pragma unroll
    for (int t = 0; t < 2; ++t) {
        int cobase = (wv * 2 + t) * 16 + quad * 4;
#pragma unroll
        for (int ph = 0; ph < 2; ++ph) {
#pragma unroll
            for (int r = 0; r < 4; ++r) {
                int co = cobase + r;
                out[((b * COUT + co) * HH + ho) * WW + wo0 + ph * 16 + l16] = acc[t][ph][r];
            }
        }
    }
}

// -------------------------------------------------------------------------
extern "C" void kernel_launch(void* const* d_in, const int* in_sizes, int n_in,
                              void* d_out, int out_size, void* d_ws, size_t ws_size,
                              hipStream_t stream) {
    const float* x  = (const float*)d_in[0];
    const float* ow = (const float*)d_in[1];
    const float* ob = (const float*)d_in[2];
    const float* mw = (const float*)d_in[3];
    const float* mb = (const float*)d_in[4];
    const float* wt = (const float*)d_in[5];

    char* ws = (char*)d_ws;
    u16* wfrag = (u16*)ws;  ws += (size_t)COUT * CK * 2;            // 576 KB
    u16* wofsf = (u16*)ws;  ws += (size_t)32 * CK * 2;              // 72 KB
    u16* xt    = (u16*)ws;                                          // 4 MB
    float* out = (float*)d_out;

    prep_all<<<1552, 256, 0, stream>>>(x, wt, ow, mw, xt, wfrag, wofsf);

    dcn_fused<<<BB * HH * 2, 512, 0, stream>>>(xt, wofsf, ob, mb, wfrag, out);
}

// Round 15
// 103.935 us; speedup vs baseline: 1.0068x; 1.0068x over previous
//
#include <hip/hip_runtime.h>
#include <math.h>

#define CIN   128
#define COUT  256
#define HH    64
#define WW    64
#define BB    4
#define KK    9
#define CK    (CIN*KK)   // 1152

typedef unsigned short u16;
typedef unsigned int   u32;
using f32x4  = __attribute__((ext_vector_type(4))) float;
using s16x8  = __attribute__((ext_vector_type(8))) short;

__device__ __forceinline__ u16 f2bf(float f) {
    union { float f; u32 u; } v; v.f = f;
    u32 u = v.u;
    u += 0x7FFFu + ((u >> 16) & 1u);   // round-to-nearest-even
    return (u16)(u >> 16);
}
__device__ __forceinline__ float bfel(s16x8 v, int j) {
    union { u32 u; float f; } c; c.u = ((u32)(u16)v[j]) << 16; return c.f;
}
__device__ __forceinline__ u32 asu(float f) {
    union { float f; u32 u; } v; v.f = f; return v.u;
}

// -------------------------------------------------------------------------
// prep_all: xt NHWC bf16; W fragment-ordered:
//  wfrag idx = ((((tap*8+wv)*2+t)*4+ks4)*512) + lane*8 + j   (8KB/tap/wave)
//  wofsf idx = (((tap*2+t)*4+ks4)*512) + lane*8 + j          (8KB/tap)
// -------------------------------------------------------------------------
__global__ __launch_bounds__(256)
void prep_all(const float* __restrict__ x, const float* __restrict__ w,
              const float* __restrict__ ow, const float* __restrict__ mw,
              u16* __restrict__ xt, u16* __restrict__ wfrag,
              u16* __restrict__ wofsf) {
    __shared__ u16 T[64][130];
    int blk = blockIdx.x;
    int tid = threadIdx.x;

    if (blk < 256) {                         // ---- xprep ----
        int b = blk >> 6, y = blk & 63;
        int lane = tid & 63, cw = tid >> 6;
        for (int c = cw; c < 128; c += 4)
            T[lane][c] = f2bf(x[((b * 128 + c) * 64 + y) * 64 + lane]);
        __syncthreads();
        int c = tid & 127;
        for (int p = tid >> 7; p < 64; p += 2)
            xt[((b * 64 + y) * 64 + p) * 128 + c] = T[p][c];
    } else if (blk < 256 + 1152) {           // ---- wprep ----
        int i = (blk - 256) * 256 + tid;
        int j    = i & 7;
        int lane = (i >> 3) & 63;
        int ks4  = (i >> 9) & 3;
        int t    = (i >> 11) & 1;
        int wv   = (i >> 12) & 7;
        int tap  = i >> 15;                  // 0..8
        int co = (wv * 2 + t) * 16 + (lane & 15);
        int k  = tap * 128 + ks4 * 32 + (lane >> 4) * 8 + j;
        int c  = k & 127;
        wfrag[i] = f2bf(w[co * CK + c * 9 + tap]);
    } else {                                 // ---- wofs_prep ----
        int i = (blk - 1408) * 256 + tid;
        if (i < 9 * 4096) {
            int j    = i & 7;
            int lane = (i >> 3) & 63;
            int ks4  = (i >> 9) & 3;
            int t    = (i >> 11) & 1;
            int tap  = i >> 12;              // 0..8
            int co = t * 16 + (lane & 15);
            int k  = tap * 128 + ks4 * 32 + (lane >> 4) * 8 + j;
            int c  = k & 127;
            float v = 0.f;
            if (co < 18)      v = ow[co * CK + c * 9 + tap];
            else if (co < 27) v = mw[(co - 18) * CK + c * 9 + tap];
            wofsf[i] = f2bf(v);
        }
    }
}

// -------------------------------------------------------------------------
// Fused kernel (r13, best measured): two taps per barrier in both phases,
// 4-slot Sm (34.8KB). Phase A staged via LDS, waves 0-1 do the offset/mask
// MFMAs; phase B: NHWC 16B corner gathers, 2-tap lookahead, fragment-
// ordered W direct loads.
// -------------------------------------------------------------------------
__global__ __launch_bounds__(512, 4)
void dcn_fused(const u16* __restrict__ xt, const u16* __restrict__ wofsf,
               const float* __restrict__ ob, const float* __restrict__ mb,
               const u16* __restrict__ wfrag, float* __restrict__ out) {
    int blkid = blockIdx.x;          // 512 = BB*HH*2
    int xcd = blkid & 7, idx = blkid >> 3;
    int b   = xcd >> 1;
    int ho  = ((xcd & 1) << 5) + (idx >> 1);
    int wo0 = (idx & 1) << 5;
    int tid = threadIdx.x;

    __shared__ __align__(16) u16 Sm[4][32][136];  // 34.8 KB, 4 tap slots
    __shared__ float s_om[27][32];
    __shared__ int   s_idx[32][KK][4];  // corner pos * 128 (xt units)
    __shared__ float s_wgt[32][KK][4];

    int wv   = tid >> 6, lane = tid & 63;
    int quad = lane >> 4, l16 = lane & 15;
    int gpx  = wv * 4 + (lane >> 4);    // px this lane stages (0..31)
    int oct  = lane & 15;               // channel-oct (8 ch)

    const u16* xtb = xt + (size_t)b * 4096 * 128;
    const s16x8 vzero = {0,0,0,0,0,0,0,0};

    // ================= phase A: offset/mask GEMM (M=32) =================
    int pa_ph = wv & 1;
    f32x4 aco[2];
    aco[0] = (f32x4)(0.f); aco[1] = (f32x4)(0.f);

    s16x8 sA[2][2];                     // [slot-pair][tap-in-pair]
    auto pa_gather = [&](int tap, int sp, int ti) {
        int kx = tap % 3;
        int y  = ho - 1 + tap / 3;
        bool yok = (unsigned)y < HH;
        int col = wo0 + gpx + kx - 1;
        bool ok = yok && ((unsigned)col < WW);
        int yc = yok ? y : 0;
        int cc = ((unsigned)col < WW) ? col : 0;
        s16x8 v = *(const s16x8*)(xtb + (size_t)(yc * 64 + cc) * 128 + oct * 8);
        sA[sp][ti] = ok ? v : vzero;
    };

    auto pa_mfma_tap = [&](int tap, int slot) {
        const u16* wc = wofsf + tap * 4096 + lane * 8;
#pragma unroll
        for (int ks4 = 0; ks4 < 4; ++ks4) {
            s16x8 bfrag = *(const s16x8*)(&Sm[slot][pa_ph * 16 + l16][ks4 * 32 + quad * 8]);
#pragma unroll
            for (int t = 0; t < 2; ++t) {
                s16x8 afrag = *(const s16x8*)(wc + (t * 4 + ks4) * 512);
                aco[t] = __builtin_amdgcn_mfma_f32_16x16x32_bf16(afrag, bfrag, aco[t], 0, 0, 0);
            }
        }
    };

    pa_gather(0, 0, 0);
    pa_gather(1, 0, 1);
#pragma unroll
    for (int p = 0; p < 4; ++p) {       // tap pairs (0,1)(2,3)(4,5)(6,7)
        int sp = p & 1;
        *(s16x8*)(&Sm[2 * sp    ][gpx][oct * 8]) = sA[sp][0];
        *(s16x8*)(&Sm[2 * sp + 1][gpx][oct * 8]) = sA[sp][1];
        __syncthreads();
        if (p < 3) { pa_gather(2 * p + 2, sp ^ 1, 0); pa_gather(2 * p + 3, sp ^ 1, 1); }
        else       { pa_gather(8,         sp ^ 1, 0); }
        if (wv < 2) {                   // waves >=2 are redundant in phase A
            pa_mfma_tap(2 * p,     2 * sp);
            pa_mfma_tap(2 * p + 1, 2 * sp + 1);
        }
    }
    // tail: tap 8 (in sA[0][0]; Sm[0] last read at p=2, barrier p=3 since)
    *(s16x8*)(&Sm[0][gpx][oct * 8]) = sA[0][0];
    __syncthreads();
    if (wv < 2) pa_mfma_tap(8, 0);

    // epilogue A: wave 0 -> px half 0, wave 1 -> px half 1
    if (wv < 2) {
#pragma unroll
        for (int t = 0; t < 2; ++t) {
#pragma unroll
            for (int r = 0; r < 4; ++r) {
                int co = t * 16 + quad * 4 + r;
                if (co < 27) {
                    float v = aco[t][r];
                    if (co < 18) {
                        v += ob[co];
                        v = fminf(fmaxf(v, -16.f), 16.f);   // max_offset = 16
                    } else {
                        v += mb[co - 18];
                        v = 2.f / (1.f + expf(-v));         // 2*sigmoid
                    }
                    s_om[co][pa_ph * 16 + l16] = v;
                }
            }
        }
    }
    __syncthreads();

    // bilinear corner params for 32 px x 9 taps
    if (tid < 32 * KK) {
        int p = tid / KK, k = tid - (tid / KK) * KK;
        int wo = wo0 + p;
        float offy = s_om[2 * k][p];
        float offx = s_om[2 * k + 1][p];
        float mval = s_om[18 + k][p];

        float py = (float)(ho - 1 + k / 3) + offy;
        float px = (float)(wo - 1 + k % 3) + offx;
        float y0f = floorf(py), x0f = floorf(px);
        float wy1 = py - y0f,  wx1 = px - x0f;
        float wy0 = 1.f - wy1, wx0 = 1.f - wx1;
        int iy0 = (int)y0f, ix0 = (int)x0f;
        int iy1 = iy0 + 1,  ix1 = ix0 + 1;
        bool vy0 = (iy0 >= 0) && (iy0 < HH);
        bool vy1 = (iy1 >= 0) && (iy1 < HH);
        bool vx0 = (ix0 >= 0) && (ix0 < WW);
        bool vx1 = (ix1 >= 0) && (ix1 < WW);
        int cy0 = min(max(iy0, 0), HH - 1), cy1 = min(max(iy1, 0), HH - 1);
        int cx0 = min(max(ix0, 0), WW - 1), cx1 = min(max(ix1, 0), WW - 1);
        s_idx[p][k][0] = (cy0 * WW + cx0) * 128;
        s_idx[p][k][1] = (cy0 * WW + cx1) * 128;
        s_idx[p][k][2] = (cy1 * WW + cx0) * 128;
        s_idx[p][k][3] = (cy1 * WW + cx1) * 128;
        s_wgt[p][k][0] = (vy0 && vx0) ? mval * wy0 * wx0 : 0.f;
        s_wgt[p][k][1] = (vy0 && vx1) ? mval * wy0 * wx1 : 0.f;
        s_wgt[p][k][2] = (vy1 && vx0) ? mval * wy1 * wx0 : 0.f;
        s_wgt[p][k][3] = (vy1 && vx1) ? mval * wy1 * wx1 : 0.f;
    }
    __syncthreads();

    // ================= phase B: sampling + main GEMM =================
    f32x4 acc[2][2];                 // [co-tile t][px half ph]
#pragma unroll
    for (int t = 0; t < 2; ++t) { acc[t][0] = (f32x4)(0.f); acc[t][1] = (f32x4)(0.f); }

    s16x8 crs[2][2][4];              // [slot-pair][tap-in-pair][corner]
    float gs[2][2][4];
    auto gatherB = [&](int tap, int sp, int ti) {
        int i0 = s_idx[gpx][tap][0], i1 = s_idx[gpx][tap][1];
        int i2 = s_idx[gpx][tap][2], i3 = s_idx[gpx][tap][3];
        gs[sp][ti][0] = s_wgt[gpx][tap][0]; gs[sp][ti][1] = s_wgt[gpx][tap][1];
        gs[sp][ti][2] = s_wgt[gpx][tap][2]; gs[sp][ti][3] = s_wgt[gpx][tap][3];
        int co8 = oct * 8;
        crs[sp][ti][0] = *(const s16x8*)(xtb + i0 + co8);
        crs[sp][ti][1] = *(const s16x8*)(xtb + i1 + co8);
        crs[sp][ti][2] = *(const s16x8*)(xtb + i2 + co8);
        crs[sp][ti][3] = *(const s16x8*)(xtb + i3 + co8);
    };

    auto blend_store = [&](int sp, int ti, int slot) {
        float g0 = gs[sp][ti][0], g1 = gs[sp][ti][1];
        float g2 = gs[sp][ti][2], g3 = gs[sp][ti][3];
        float o[8];
#pragma unroll
        for (int j = 0; j < 8; ++j)
            o[j] = g0 * bfel(crs[sp][ti][0], j) + g1 * bfel(crs[sp][ti][1], j)
                 + g2 * bfel(crs[sp][ti][2], j) + g3 * bfel(crs[sp][ti][3], j);
        uint4 pkv;
        pkv.x = (asu(o[1]) & 0xFFFF0000u) | (asu(o[0]) >> 16);
        pkv.y = (asu(o[3]) & 0xFFFF0000u) | (asu(o[2]) >> 16);
        pkv.z = (asu(o[5]) & 0xFFFF0000u) | (asu(o[4]) >> 16);
        pkv.w = (asu(o[7]) & 0xFFFF0000u) | (asu(o[6]) >> 16);
        *(uint4*)(&Sm[slot][gpx][oct * 8]) = pkv;
    };

    auto pb_mfma_tap = [&](int tap, int slot) {
        const u16* wc = wfrag + (tap * 8 + wv) * 4096 + lane * 8;
        s16x8 af[8];
#pragma unroll
        for (int t = 0; t < 2; ++t)
#pragma unroll
            for (int ks4 = 0; ks4 < 4; ++ks4)
                af[t * 4 + ks4] = *(const s16x8*)(wc + (t * 4 + ks4) * 512);
#pragma unroll
        for (int ks4 = 0; ks4 < 4; ++ks4) {
            s16x8 bf0 = *(const s16x8*)(&Sm[slot][l16][ks4 * 32 + quad * 8]);
            s16x8 bf1 = *(const s16x8*)(&Sm[slot][16 + l16][ks4 * 32 + quad * 8]);
#pragma unroll
            for (int t = 0; t < 2; ++t) {
                acc[t][0] = __builtin_amdgcn_mfma_f32_16x16x32_bf16(af[t * 4 + ks4], bf0, acc[t][0], 0, 0, 0);
                acc[t][1] = __builtin_amdgcn_mfma_f32_16x16x32_bf16(af[t * 4 + ks4], bf1, acc[t][1], 0, 0, 0);
            }
        }
    };

    gatherB(0, 0, 0);
    gatherB(1, 0, 1);
#pragma unroll
    for (int p = 0; p < 4; ++p) {       // tap pairs (0,1)(2,3)(4,5)(6,7)
        int sp = p & 1;
        blend_store(sp, 0, 2 * sp);
        blend_store(sp, 1, 2 * sp + 1);
        __syncthreads();
        if (p < 3) { gatherB(2 * p + 2, sp ^ 1, 0); gatherB(2 * p + 3, sp ^ 1, 1); }
        else       { gatherB(8,         sp ^ 1, 0); }
        pb_mfma_tap(2 * p,     2 * sp);
        pb_mfma_tap(2 * p + 1, 2 * sp + 1);
    }
    // tail: tap 8
    blend_store(0, 0, 0);
    __syncthreads();
    pb_mfma_tap(8, 0);

    // epilogue: co = (wv*2+t)*16 + quad*4 + r; px = wo0 + ph*16 + l16
#pragma unroll
    for (int t = 0; t < 2; ++t) {
        int cobase = (wv * 2 + t) * 16 + quad * 4;
#pragma unroll
        for (int ph = 0; ph < 2; ++ph) {
#pragma unroll
            for (int r = 0; r < 4; ++r) {
                int co = cobase + r;
                out[((b * COUT + co) * HH + ho) * WW + wo0 + ph * 16 + l16] = acc[t][ph][r];
            }
        }
    }
}

// -------------------------------------------------------------------------
extern "C" void kernel_launch(void* const* d_in, const int* in_sizes, int n_in,
                              void* d_out, int out_size, void* d_ws, size_t ws_size,
                              hipStream_t stream) {
    const float* x  = (const float*)d_in[0];
    const float* ow = (const float*)d_in[1];
    const float* ob = (const float*)d_in[2];
    const float* mw = (const float*)d_in[3];
    const float* mb = (const float*)d_in[4];
    const float* wt = (const float*)d_in[5];

    char* ws = (char*)d_ws;
    u16* wfrag = (u16*)ws;  ws += (size_t)COUT * CK * 2;            // 576 KB
    u16* wofsf = (u16*)ws;  ws += (size_t)32 * CK * 2;              // 72 KB
    u16* xt    = (u16*)ws;                                          // 4 MB
    float* out = (float*)d_out;

    prep_all<<<1552, 256, 0, stream>>>(x, wt, ow, mw, xt, wfrag, wofsf);

    dcn_fused<<<BB * HH * 2, 512, 0, stream>>>(xt, wofsf, ob, mb, wfrag, out);
}